// Round 1
// 162.382 us; speedup vs baseline: 1.1051x; 1.1051x over previous
//
#include <hip/hip_runtime.h>
#include <hip/hip_bf16.h>

// CAM: per batch b (B=16):  a = x[b] viewed as [N=4096, C=256]
//   aTa  = a^T a            [C, C]
//   attn = softmax(aTa, -1)
//   y    = a · attn         [N, C]
//   out  = gamma * y + x
// Storage: fp32 (values bf16-quantized by harness). Internal: bf16 MFMA, fp32 accum.
//
// R(this): k_transpose ELIMINATED — gemm1 reads x directly, does bf16-cvt +
// transpose in registers, stages the [c][n] panel once per block (aTa is
// symmetric: the same LDS panel feeds both MFMA operands). Split-K partials
// (no atomics — earlier session showed the atomic epilogue serialized).
// Grid (split, b, half): halves of a (b,split) pair are 128 apart in linear
// wg-id => same XCD => shared x-panel L2-served to the twin block.
// LDS slot XOR-swizzle (key=(c>>2)&7, 8-slot chunks) makes the transposed
// ds_write_b128 bank-conflict-free; the induced k-permutation is identical
// for A and B fragments (both read with the row-keyed XOR), so the MFMA
// reduction is over the same n set — verified by hand since gamma==0 makes
// the harness absmax blind to gemm1 errors.

#define BB 16
#define NN 4096   // H*W
#define CC 256
#define SPLITK 8
#define KCHUNK (NN / SPLITK)   // 512

typedef __attribute__((ext_vector_type(4))) short short4v;
typedef __attribute__((ext_vector_type(8))) short short8v;
typedef __attribute__((ext_vector_type(4))) float floatx4;

__device__ __forceinline__ unsigned short f2bf(float f) {
    unsigned int u = __float_as_uint(f);
    u += 0x7fffu + ((u >> 16) & 1u);   // RNE (exact for already-bf16-grid values)
    return (unsigned short)(u >> 16);
}
__device__ __forceinline__ short4v cvt4(floatx4 v) {
    short4v r;
    r[0] = (short)f2bf(v[0]); r[1] = (short)f2bf(v[1]);
    r[2] = (short)f2bf(v[2]); r[3] = (short)f2bf(v[3]);
    return r;
}

// ---------------- K1: part[split][b] = partial a^T a (fused transpose) ----
// grid (SPLITK, BB, 2) = 256 blocks, 256 threads (4 waves), 1 block/CU.
// Block: rows [half*128, half*128+128) x all 256 cols, k-range of 512 n.
// Per 64-n step: lane loads 16 rows x 4 ch (floatx4), cvt+transpose in regs,
// writes swizzled short8v columns into P[c][slot]; wave w owns slots
// [16w,16w+16). n(slot'): s' = slot^key(c)<<3; n = (s'>>4) + 4*(s'&15) —
// row-independent, bijective over 0..63, identical for af and bf reads.
__global__ __launch_bounds__(256, 1) void k_gemm1(const float* __restrict__ x,
                                                  float* __restrict__ part) {
    __shared__ unsigned short P[256 * 72];   // [c][64 slots + pad], 36.9 KB
    const int split = blockIdx.x;
    const int b     = blockIdx.y;
    const int half  = blockIdx.z;
    const int t  = threadIdx.x;
    const int w  = t >> 6, l = t & 63;
    const int lk = (l >> 4) * 8;
    const int lm = l & 15;
    const int i0 = half * 128;
    const int wr = (w >> 1) * 64;            // wave tile 64 x 128
    const int wc = (w & 1) * 128;
    const unsigned swz = (unsigned)(l & 7) << 3;   // == ((c>>2)&7)<<3 for c=4l+j

    const float* xb = x + ((size_t)b * NN + (size_t)split * KCHUNK) * CC + 4 * l;

    floatx4 pf[16];
    #pragma unroll
    for (int p = 0; p < 16; ++p)
        pf[p] = *(const floatx4*)(xb + (size_t)(w + 4 * p) * CC);   // n = w + 4p

    floatx4 acc[4][8] = {};

    for (int k0 = 0; k0 < KCHUNK; k0 += 64) {
        // bf16 convert + in-register 16x4 -> 4x16 transpose
        short4v s[16];
        #pragma unroll
        for (int p = 0; p < 16; ++p) s[p] = cvt4(pf[p]);
        #pragma unroll
        for (int j = 0; j < 4; ++j) {
            short8v oA, oB;
            #pragma unroll
            for (int e = 0; e < 8; ++e) { oA[e] = s[e][j]; oB[e] = s[e + 8][j]; }
            const unsigned c = (unsigned)(4 * l + j);
            *(short8v*)&P[c * 72 + (((unsigned)(16 * w))     ^ swz)] = oA;
            *(short8v*)&P[c * 72 + (((unsigned)(16 * w + 8)) ^ swz)] = oB;
        }
        __syncthreads();
        // prefetch next 64-n chunk (completes under the MFMA phase)
        if (k0 + 64 < KCHUNK) {
            const float* xn = xb + (size_t)(k0 + 64) * CC;
            #pragma unroll
            for (int p = 0; p < 16; ++p)
                pf[p] = *(const floatx4*)(xn + (size_t)(w + 4 * p) * CC);
        }
        #pragma unroll
        for (int ks = 0; ks < 64; ks += 32) {
            short8v af[4], bf[8];
            #pragma unroll
            for (int mt = 0; mt < 4; ++mt) {
                const unsigned row = (unsigned)(i0 + wr + mt * 16 + lm);
                af[mt] = *(const short8v*)&P[row * 72 + (((unsigned)(ks + lk)) ^ (((row >> 2) & 7u) << 3))];
            }
            #pragma unroll
            for (int nt = 0; nt < 8; ++nt) {
                const unsigned row = (unsigned)(wc + nt * 16 + lm);
                bf[nt] = *(const short8v*)&P[row * 72 + (((unsigned)(ks + lk)) ^ (((row >> 2) & 7u) << 3))];
            }
            #pragma unroll
            for (int mt = 0; mt < 4; ++mt)
                #pragma unroll
                for (int nt = 0; nt < 8; ++nt)
                    acc[mt][nt] = __builtin_amdgcn_mfma_f32_16x16x32_bf16(af[mt], bf[nt], acc[mt][nt], 0, 0, 0);
        }
        __syncthreads();
    }
    const int orow = (l >> 4) * 4;    // C/D: row=(lane>>4)*4+r, col=lane&15
    float* pout = part + (size_t)(split * BB + b) * CC * CC;
    #pragma unroll
    for (int mt = 0; mt < 4; ++mt)
        #pragma unroll
        for (int nt = 0; nt < 8; ++nt)
            #pragma unroll
            for (int r = 0; r < 4; ++r) {
                int i = i0 + wr + mt * 16 + orow + r;
                int j = wc + nt * 16 + lm;
                pout[(size_t)i * CC + j] = acc[mt][nt][r];
            }
}

// ---------------- K2: attn_T[b][j][i] = softmax over summed partials ----
__global__ __launch_bounds__(256) void k_softmax(const float* __restrict__ part,
                                                 unsigned short* __restrict__ attnT) {
    const int w = threadIdx.x >> 6;
    const int l = threadIdx.x & 63;
    const int row = blockIdx.x * 4 + w;   // 0..B*C-1
    const int b = row >> 8;
    const int i = row & 255;
    float v0 = 0.f, v1 = 0.f, v2 = 0.f, v3 = 0.f;
    #pragma unroll
    for (int s = 0; s < SPLITK; ++s) {
        const float* p = part + ((size_t)(s * BB + b) * CC + i) * CC;
        v0 += p[l]; v1 += p[l + 64]; v2 += p[l + 128]; v3 += p[l + 192];
    }
    float m = fmaxf(fmaxf(v0, v1), fmaxf(v2, v3));
    for (int off = 32; off >= 1; off >>= 1) m = fmaxf(m, __shfl_xor(m, off, 64));
    v0 = __expf(v0 - m); v1 = __expf(v1 - m); v2 = __expf(v2 - m); v3 = __expf(v3 - m);
    float s = v0 + v1 + v2 + v3;
    for (int off = 32; off >= 1; off >>= 1) s += __shfl_xor(s, off, 64);
    float rs = 1.0f / s;
    unsigned short* o = attnT + (size_t)b * CC * CC + i;   // attnT[b][j][i]
    o[(size_t)(l +   0) * CC] = f2bf(v0 * rs);
    o[(size_t)(l +  64) * CC] = f2bf(v1 * rs);
    o[(size_t)(l + 128) * CC] = f2bf(v2 * rs);
    o[(size_t)(l + 192) * CC] = f2bf(v3 * rs);
}

// ---------------- K3: out = gamma * (a · attn) + x ----------------------
// Block tile: 64 n-rows x ALL 256 j. grid (64, BB) = 1024 blocks.
// x staged exactly once (k-loop unions to the full row panel).
__global__ __launch_bounds__(256) void k_gemm2(const float* __restrict__ x,
                                               const unsigned short* __restrict__ attnT,
                                               const float* __restrict__ gamma,
                                               float* __restrict__ out) {
    __shared__ unsigned short At[64 * 72];    // [n_local][k]
    __shared__ unsigned short Bt[256 * 72];   // [j][k]
    const int n0 = blockIdx.x * 64;
    const int b  = blockIdx.y;
    const int t  = threadIdx.x;
    const int w  = t >> 6, l = t & 63;
    const int lk = (l >> 4) * 8, lm = l & 15;
    const int sc = t >> 4, sk = (t & 15) * 4;

    const float*          Abase = x + ((size_t)b * NN + n0) * CC;
    const unsigned short* Bbase = attnT + (size_t)b * CC * CC;

    floatx4 acc[4][4] = {};
    for (int k0 = 0; k0 < CC; k0 += 64) {
        #pragma unroll
        for (int r = 0; r < 4; ++r) {
            int n = sc + 16 * r;
            floatx4 av = *(const floatx4*)(Abase + (size_t)n * CC + k0 + sk);
            *(short4v*)&At[n * 72 + sk] = cvt4(av);
        }
        #pragma unroll
        for (int r = 0; r < 16; ++r) {
            int j = sc + 16 * r;
            *(short4v*)&Bt[j * 72 + sk] = *(const short4v*)(Bbase + (size_t)j * CC + k0 + sk);
        }
        __syncthreads();
        #pragma unroll
        for (int ks = 0; ks < 64; ks += 32) {
            short8v af[4], bf[4];
            #pragma unroll
            for (int mt = 0; mt < 4; ++mt)
                af[mt] = *(const short8v*)&At[(mt * 16 + lm) * 72 + ks + lk];
            #pragma unroll
            for (int nt = 0; nt < 4; ++nt)
                bf[nt] = *(const short8v*)&Bt[(w * 64 + nt * 16 + lm) * 72 + ks + lk];
            #pragma unroll
            for (int mt = 0; mt < 4; ++mt)
                #pragma unroll
                for (int nt = 0; nt < 4; ++nt)
                    acc[mt][nt] = __builtin_amdgcn_mfma_f32_16x16x32_bf16(af[mt], bf[nt], acc[mt][nt], 0, 0, 0);
        }
        __syncthreads();
    }
    const float g = gamma[0];
    const int orow = (l >> 4) * 4;
    #pragma unroll
    for (int mt = 0; mt < 4; ++mt)
        #pragma unroll
        for (int nt = 0; nt < 4; ++nt)
            #pragma unroll
            for (int r = 0; r < 4; ++r) {
                int nr = n0 + mt * 16 + orow + r;
                int j  = w * 64 + nt * 16 + lm;
                size_t idx = ((size_t)b * NN + nr) * CC + j;
                out[idx] = g * acc[mt][nt][r] + x[idx];
            }
}

extern "C" void kernel_launch(void* const* d_in, const int* in_sizes, int n_in,
                              void* d_out, int out_size, void* d_ws, size_t ws_size,
                              hipStream_t stream) {
    const float* x     = (const float*)d_in[0];
    const float* gamma = (const float*)d_in[1];
    float* out = (float*)d_out;

    char* ws = (char*)d_ws;
    float*          part  = (float*)ws;                                   // 8*16*256*256*4 = 32 MB
    unsigned short* attnT = (unsigned short*)(ws + (size_t)SPLITK * BB * CC * CC * 4);  // 2 MB

    k_gemm1  <<<dim3(SPLITK, BB, 2),  256, 0, stream>>>(x, part);
    k_softmax<<<dim3(BB * CC / 4),    256, 0, stream>>>(part, attnT);
    k_gemm2  <<<dim3(NN / 64, BB),    256, 0, stream>>>(x, attnT, gamma, out);
}

// Round 2
// 159.830 us; speedup vs baseline: 1.1228x; 1.0160x over previous
//
#include <hip/hip_runtime.h>
#include <hip/hip_bf16.h>

// CAM: per batch b (B=16):  a = x[b] viewed as [N=4096, C=256]
//   aTa  = a^T a            [C, C]
//   attn = softmax(aTa, -1)
//   y    = a · attn         [N, C]
//   out  = gamma * y + x
// Storage: fp32 (values bf16-quantized by harness). Internal: bf16 MFMA, fp32 accum.
//
// R1->R2: k_gemm1 was 256 blocks x 4 waves = 1 wave/SIMD (zero latency hiding;
// total time ~= old aT-fed version despite less traffic). Now 512 threads =
// 8 waves/block -> 2 waves/SIMD, wave tile 64x64 (acc[4][4], VGPR ~150 vs ~250).
// Same grid/panel/L2-pairing structure. Slot map: wave w writes short8v at
// chunk 8w; pre-swizzle slot s holds n = (s>>3) + 8*(s&7) (bijective).
// XOR swizzle key (c>>2)&7 on 8-slot chunks: read XOR cancels write XOR
// per-row, so effective k-permutation pi(k)=n_map(ks+k) is row-independent
// and IDENTICAL for A and B fragments (hand-verified again; gamma==0 makes
// the harness absmax blind to gemm1 errors, so this must be right by proof).

#define BB 16
#define NN 4096   // H*W
#define CC 256
#define SPLITK 8
#define KCHUNK (NN / SPLITK)   // 512

typedef __attribute__((ext_vector_type(4))) short short4v;
typedef __attribute__((ext_vector_type(8))) short short8v;
typedef __attribute__((ext_vector_type(4))) float floatx4;

__device__ __forceinline__ unsigned short f2bf(float f) {
    unsigned int u = __float_as_uint(f);
    u += 0x7fffu + ((u >> 16) & 1u);   // RNE (exact for already-bf16-grid values)
    return (unsigned short)(u >> 16);
}
__device__ __forceinline__ short4v cvt4(floatx4 v) {
    short4v r;
    r[0] = (short)f2bf(v[0]); r[1] = (short)f2bf(v[1]);
    r[2] = (short)f2bf(v[2]); r[3] = (short)f2bf(v[3]);
    return r;
}

// ---------------- K1: part[split][b] = partial a^T a (fused transpose) ----
// grid (SPLITK, BB, 2) = 256 blocks, 512 threads (8 waves), 2 waves/SIMD.
// Block: rows [half*128, half*128+128) x all 256 cols, k-range of 512 n.
// Per 64-n step: lane loads 8 rows x 4 ch (floatx4), cvt+transpose in regs,
// writes swizzled short8v columns into P[c][slot]; wave w owns chunk
// [8w, 8w+8). Wave tiles: 2 (rows) x 4 (cols) of 64x64.
__global__ __launch_bounds__(512, 2) void k_gemm1(const float* __restrict__ x,
                                                  float* __restrict__ part) {
    __shared__ unsigned short P[256 * 72];   // [c][64 slots + pad], 36.9 KB
    const int split = blockIdx.x;
    const int b     = blockIdx.y;
    const int half  = blockIdx.z;
    const int t  = threadIdx.x;
    const int w  = t >> 6, l = t & 63;
    const int lk = (l >> 4) * 8;
    const int lm = l & 15;
    const int i0 = half * 128;
    const int wr = (w >> 2) * 64;            // wave tile 64 x 64
    const int wc = (w & 3) * 64;
    const unsigned swz = (unsigned)(l & 7) << 3;   // == ((c>>2)&7)<<3 for c=4l+j

    const float* xb = x + ((size_t)b * NN + (size_t)split * KCHUNK) * CC + 4 * l;

    floatx4 pf[8];
    #pragma unroll
    for (int p = 0; p < 8; ++p)
        pf[p] = *(const floatx4*)(xb + (size_t)(w + 8 * p) * CC);   // n = w + 8p

    floatx4 acc[4][4] = {};

    for (int k0 = 0; k0 < KCHUNK; k0 += 64) {
        // bf16 convert + in-register 8x4 -> 4x8 transpose
        short4v s[8];
        #pragma unroll
        for (int p = 0; p < 8; ++p) s[p] = cvt4(pf[p]);
        #pragma unroll
        for (int j = 0; j < 4; ++j) {
            short8v o;
            #pragma unroll
            for (int e = 0; e < 8; ++e) o[e] = s[e][j];   // n = w + 8e
            const unsigned c = (unsigned)(4 * l + j);
            *(short8v*)&P[c * 72 + (((unsigned)(8 * w)) ^ swz)] = o;
        }
        __syncthreads();
        // prefetch next 64-n chunk (completes under the MFMA phase)
        if (k0 + 64 < KCHUNK) {
            const float* xn = xb + (size_t)(k0 + 64) * CC;
            #pragma unroll
            for (int p = 0; p < 8; ++p)
                pf[p] = *(const floatx4*)(xn + (size_t)(w + 8 * p) * CC);
        }
        #pragma unroll
        for (int ks = 0; ks < 64; ks += 32) {
            short8v af[4], bf[4];
            #pragma unroll
            for (int mt = 0; mt < 4; ++mt) {
                const unsigned row = (unsigned)(i0 + wr + mt * 16 + lm);
                af[mt] = *(const short8v*)&P[row * 72 + (((unsigned)(ks + lk)) ^ (((row >> 2) & 7u) << 3))];
            }
            #pragma unroll
            for (int nt = 0; nt < 4; ++nt) {
                const unsigned row = (unsigned)(wc + nt * 16 + lm);
                bf[nt] = *(const short8v*)&P[row * 72 + (((unsigned)(ks + lk)) ^ (((row >> 2) & 7u) << 3))];
            }
            #pragma unroll
            for (int mt = 0; mt < 4; ++mt)
                #pragma unroll
                for (int nt = 0; nt < 4; ++nt)
                    acc[mt][nt] = __builtin_amdgcn_mfma_f32_16x16x32_bf16(af[mt], bf[nt], acc[mt][nt], 0, 0, 0);
        }
        __syncthreads();
    }
    const int orow = (l >> 4) * 4;    // C/D: row=(lane>>4)*4+r, col=lane&15
    float* pout = part + (size_t)(split * BB + b) * CC * CC;
    #pragma unroll
    for (int mt = 0; mt < 4; ++mt)
        #pragma unroll
        for (int nt = 0; nt < 4; ++nt)
            #pragma unroll
            for (int r = 0; r < 4; ++r) {
                int i = i0 + wr + mt * 16 + orow + r;
                int j = wc + nt * 16 + lm;
                pout[(size_t)i * CC + j] = acc[mt][nt][r];
            }
}

// ---------------- K2: attn_T[b][j][i] = softmax over summed partials ----
__global__ __launch_bounds__(256) void k_softmax(const float* __restrict__ part,
                                                 unsigned short* __restrict__ attnT) {
    const int w = threadIdx.x >> 6;
    const int l = threadIdx.x & 63;
    const int row = blockIdx.x * 4 + w;   // 0..B*C-1
    const int b = row >> 8;
    const int i = row & 255;
    float v0 = 0.f, v1 = 0.f, v2 = 0.f, v3 = 0.f;
    #pragma unroll
    for (int s = 0; s < SPLITK; ++s) {
        const float* p = part + ((size_t)(s * BB + b) * CC + i) * CC;
        v0 += p[l]; v1 += p[l + 64]; v2 += p[l + 128]; v3 += p[l + 192];
    }
    float m = fmaxf(fmaxf(v0, v1), fmaxf(v2, v3));
    for (int off = 32; off >= 1; off >>= 1) m = fmaxf(m, __shfl_xor(m, off, 64));
    v0 = __expf(v0 - m); v1 = __expf(v1 - m); v2 = __expf(v2 - m); v3 = __expf(v3 - m);
    float s = v0 + v1 + v2 + v3;
    for (int off = 32; off >= 1; off >>= 1) s += __shfl_xor(s, off, 64);
    float rs = 1.0f / s;
    unsigned short* o = attnT + (size_t)b * CC * CC + i;   // attnT[b][j][i]
    o[(size_t)(l +   0) * CC] = f2bf(v0 * rs);
    o[(size_t)(l +  64) * CC] = f2bf(v1 * rs);
    o[(size_t)(l + 128) * CC] = f2bf(v2 * rs);
    o[(size_t)(l + 192) * CC] = f2bf(v3 * rs);
}

// ---------------- K3: out = gamma * (a · attn) + x ----------------------
// Block tile: 64 n-rows x ALL 256 j. grid (64, BB) = 1024 blocks.
// x staged exactly once (k-loop unions to the full row panel).
__global__ __launch_bounds__(256) void k_gemm2(const float* __restrict__ x,
                                               const unsigned short* __restrict__ attnT,
                                               const float* __restrict__ gamma,
                                               float* __restrict__ out) {
    __shared__ unsigned short At[64 * 72];    // [n_local][k]
    __shared__ unsigned short Bt[256 * 72];   // [j][k]
    const int n0 = blockIdx.x * 64;
    const int b  = blockIdx.y;
    const int t  = threadIdx.x;
    const int w  = t >> 6, l = t & 63;
    const int lk = (l >> 4) * 8, lm = l & 15;
    const int sc = t >> 4, sk = (t & 15) * 4;

    const float*          Abase = x + ((size_t)b * NN + n0) * CC;
    const unsigned short* Bbase = attnT + (size_t)b * CC * CC;

    floatx4 acc[4][4] = {};
    for (int k0 = 0; k0 < CC; k0 += 64) {
        #pragma unroll
        for (int r = 0; r < 4; ++r) {
            int n = sc + 16 * r;
            floatx4 av = *(const floatx4*)(Abase + (size_t)n * CC + k0 + sk);
            *(short4v*)&At[n * 72 + sk] = cvt4(av);
        }
        #pragma unroll
        for (int r = 0; r < 16; ++r) {
            int j = sc + 16 * r;
            *(short4v*)&Bt[j * 72 + sk] = *(const short4v*)(Bbase + (size_t)j * CC + k0 + sk);
        }
        __syncthreads();
        #pragma unroll
        for (int ks = 0; ks < 64; ks += 32) {
            short8v af[4], bf[4];
            #pragma unroll
            for (int mt = 0; mt < 4; ++mt)
                af[mt] = *(const short8v*)&At[(mt * 16 + lm) * 72 + ks + lk];
            #pragma unroll
            for (int nt = 0; nt < 4; ++nt)
                bf[nt] = *(const short8v*)&Bt[(w * 64 + nt * 16 + lm) * 72 + ks + lk];
            #pragma unroll
            for (int mt = 0; mt < 4; ++mt)
                #pragma unroll
                for (int nt = 0; nt < 4; ++nt)
                    acc[mt][nt] = __builtin_amdgcn_mfma_f32_16x16x32_bf16(af[mt], bf[nt], acc[mt][nt], 0, 0, 0);
        }
        __syncthreads();
    }
    const float g = gamma[0];
    const int orow = (l >> 4) * 4;
    #pragma unroll
    for (int mt = 0; mt < 4; ++mt)
        #pragma unroll
        for (int nt = 0; nt < 4; ++nt)
            #pragma unroll
            for (int r = 0; r < 4; ++r) {
                int nr = n0 + mt * 16 + orow + r;
                int j  = w * 64 + nt * 16 + lm;
                size_t idx = ((size_t)b * NN + nr) * CC + j;
                out[idx] = g * acc[mt][nt][r] + x[idx];
            }
}

extern "C" void kernel_launch(void* const* d_in, const int* in_sizes, int n_in,
                              void* d_out, int out_size, void* d_ws, size_t ws_size,
                              hipStream_t stream) {
    const float* x     = (const float*)d_in[0];
    const float* gamma = (const float*)d_in[1];
    float* out = (float*)d_out;

    char* ws = (char*)d_ws;
    float*          part  = (float*)ws;                                   // 8*16*256*256*4 = 32 MB
    unsigned short* attnT = (unsigned short*)(ws + (size_t)SPLITK * BB * CC * CC * 4);  // 2 MB

    k_gemm1  <<<dim3(SPLITK, BB, 2),  512, 0, stream>>>(x, part);
    k_softmax<<<dim3(BB * CC / 4),    256, 0, stream>>>(part, attnT);
    k_gemm2  <<<dim3(NN / 64, BB),    256, 0, stream>>>(x, attnT, gamma, out);
}